// Round 1
// baseline (605.407 us; speedup 1.0000x reference)
//
#include <hip/hip_runtime.h>
#include <hip/hip_bf16.h>

#define B_  4
#define N_  131072
#define M_  10475
#define J_  55
#define JP_ 56        // padded J for the trilinear path (pad entry is zero)
#define D_  64
#define D3_ 262144    // 64^3
#define PF_ 486
#define COLS_ 31425   // M*3

// ---------------- off_full init: shape part (betas . spdir) ----------------
__global__ void k_off_init(const float* __restrict__ betas,
                           const float* __restrict__ spdir,
                           float* __restrict__ off_full) {
    int col = blockIdx.x * 256 + threadIdx.x;
    if (col >= COLS_) return;
    float sp[10];
#pragma unroll
    for (int l = 0; l < 10; ++l) sp[l] = spdir[col * 10 + l];
#pragma unroll
    for (int b = 0; b < B_; ++b) {
        float s = 0.f;
#pragma unroll
        for (int l = 0; l < 10; ++l) s += betas[b * 10 + l] * sp[l];
        off_full[b * COLS_ + col] = s;
    }
}

// ---------------- off_full pose part: pf @ podir, p-chunked atomics --------
__global__ void k_off_pose(const float* __restrict__ pf,
                           const float* __restrict__ podir,
                           float* __restrict__ off_full) {
    int col = blockIdx.x * 256 + threadIdx.x;
    if (col >= COLS_) return;
    int pc = blockIdx.y;
    int p0 = pc * 61;
    int p1 = p0 + 61; if (p1 > PF_) p1 = PF_;
    float a0 = 0.f, a1 = 0.f, a2 = 0.f, a3 = 0.f;
    for (int p = p0; p < p1; ++p) {
        float v = podir[(size_t)p * COLS_ + col];
        a0 += pf[0 * PF_ + p] * v;
        a1 += pf[1 * PF_ + p] * v;
        a2 += pf[2 * PF_ + p] * v;
        a3 += pf[3 * PF_ + p] * v;
    }
    atomicAdd(&off_full[0 * COLS_ + col], a0);
    atomicAdd(&off_full[1 * COLS_ + col], a1);
    atomicAdd(&off_full[2 * COLS_ + col], a2);
    atomicAdd(&off_full[3 * COLS_ + col], a3);
}

// ---------------- tfs = A @ A_inv, padded to JP_ joints --------------------
__global__ void k_tfs(const float* __restrict__ A,
                      const float* __restrict__ Ainv,
                      float* __restrict__ tfsP) {
    int tid = blockIdx.x * 256 + threadIdx.x;
    if (tid >= B_ * JP_ * 16) return;
    int rc = tid & 15;
    int jb = tid >> 4;
    int j = jb % JP_;
    int b = jb / JP_;
    float v = 0.f;
    if (j < J_) {
        int r = rc >> 2, c = rc & 3;
#pragma unroll
        for (int k = 0; k < 4; ++k)
            v += A[((b * J_ + j) * 4 + r) * 4 + k] * Ainv[(j * 4 + k) * 4 + c];
    }
    tfsP[tid] = v;
}

// ---------------- voxel transpose: [J][D3] -> [D3][64] (j-padded w/ zeros) -
__global__ void k_vox_t(const float* __restrict__ vox,
                        float* __restrict__ vox_t) {
    __shared__ float tile[64 * 65];   // [j][f], row stride 65 breaks conflicts
    int fid0 = blockIdx.x * 64;
    int t = threadIdx.x;
    // fill: 64 j-rows (zeros for j>=55) x 64 fids, coalesced reads over fid
#pragma unroll
    for (int it = 0; it < 16; ++it) {
        int idx = it * 256 + t;
        int j = idx >> 6;
        int f = idx & 63;
        float v = (j < J_) ? vox[(size_t)j * D3_ + fid0 + f] : 0.f;
        tile[j * 65 + f] = v;
    }
    __syncthreads();
    // write: coalesced over j, 256B-aligned 64-float rows per fid
#pragma unroll
    for (int it = 0; it < 16; ++it) {
        int idx = it * 256 + t;
        int f = idx >> 6;
        int j = idx & 63;
        vox_t[(size_t)(fid0 + f) * 64 + j] = tile[j * 65 + f];
    }
}

// ---------------- main fused kernel ----------------------------------------
__global__ __launch_bounds__(256) void k_main(
    const float* __restrict__ pts, const int* __restrict__ faces,
    const float* __restrict__ poseoff, const float* __restrict__ lbsw,
    const int* __restrict__ mask, const float* __restrict__ vox_scale,
    const float* __restrict__ vox_offset, const float* __restrict__ off_full,
    const float* __restrict__ tfsP, const float* __restrict__ vox_t,
    float* __restrict__ out_posed, float* __restrict__ out_T) {
    int i = blockIdx.x * 256 + threadIdx.x;       // i = b*N + n
    int n = i & (N_ - 1);
    int b = i >> 17;

    float px = pts[3 * i + 0], py = pts[3 * i + 1], pz = pts[3 * i + 2];
    int f0 = faces[3 * n + 0], f1 = faces[3 * n + 1], f2 = faces[3 * n + 2];
    const float* ob = off_full + b * COLS_;
    const float c3 = 1.f / 3.f;
    float ox = (ob[f0 * 3 + 0] + ob[f1 * 3 + 0] + ob[f2 * 3 + 0]) * c3;
    float oy = (ob[f0 * 3 + 1] + ob[f1 * 3 + 1] + ob[f2 * 3 + 1]) * c3;
    float oz = (ob[f0 * 3 + 2] + ob[f1 * 3 + 2] + ob[f2 * 3 + 2]) * c3;
    float x0 = px + ox - poseoff[3 * n + 0];
    float x1 = py + oy - poseoff[3 * n + 1];
    float x2 = pz + oz - poseoff[3 * n + 2];

    float T[16];
#pragma unroll
    for (int r = 0; r < 16; ++r) T[r] = 0.f;
    float wsum = 0.f;
    const float* tb = tfsP + b * (JP_ * 16);

    if (mask[i] > 0) {
        const float* lw = lbsw + (size_t)n * J_;
        for (int j = 0; j < J_; ++j) {
            float w = lw[j];
            wsum += w;
            const float* tr = tb + j * 16;
#pragma unroll
            for (int r = 0; r < 16; ++r) T[r] += w * tr[r];
        }
    } else {
        // trilinear on RAW pts (per reference)
        float sx = vox_scale[0], sy = vox_scale[1], sz = vox_scale[2];
        float o0 = vox_offset[0], o1 = vox_offset[1], o2 = vox_offset[2];
        float gx = fminf(fmaxf(px * sx + o0, -1.f), 1.f);
        float gy = fminf(fmaxf(py * sy + o1, -1.f), 1.f);
        float gz = fminf(fmaxf(pz * sz + o2, -1.f), 1.f);
        float tx = (gx + 1.f) * 0.5f * (D_ - 1);
        float ty = (gy + 1.f) * 0.5f * (D_ - 1);
        float tz = (gz + 1.f) * 0.5f * (D_ - 1);
        int ix = (int)floorf(tx); if (ix > D_ - 2) ix = D_ - 2; if (ix < 0) ix = 0;
        int iy = (int)floorf(ty); if (iy > D_ - 2) iy = D_ - 2; if (iy < 0) iy = 0;
        int iz = (int)floorf(tz); if (iz > D_ - 2) iz = D_ - 2; if (iz < 0) iz = 0;
        float fx = tx - ix, fy = ty - iy, fz = tz - iz;
        int base = (ix * D_ + iy) * D_ + iz;
        float w000 = (1.f - fx) * (1.f - fy) * (1.f - fz);
        float w001 = (1.f - fx) * (1.f - fy) * fz;
        float w010 = (1.f - fx) * fy * (1.f - fz);
        float w011 = (1.f - fx) * fy * fz;
        float w100 = fx * (1.f - fy) * (1.f - fz);
        float w101 = fx * (1.f - fy) * fz;
        float w110 = fx * fy * (1.f - fz);
        float w111 = fx * fy * fz;
        const float4* P0 = (const float4*)(vox_t + (size_t)(base) * 64);
        const float4* P1 = (const float4*)(vox_t + (size_t)(base + 1) * 64);
        const float4* P2 = (const float4*)(vox_t + (size_t)(base + D_) * 64);
        const float4* P3 = (const float4*)(vox_t + (size_t)(base + D_ + 1) * 64);
        const float4* P4 = (const float4*)(vox_t + (size_t)(base + D_ * D_) * 64);
        const float4* P5 = (const float4*)(vox_t + (size_t)(base + D_ * D_ + 1) * 64);
        const float4* P6 = (const float4*)(vox_t + (size_t)(base + D_ * D_ + D_) * 64);
        const float4* P7 = (const float4*)(vox_t + (size_t)(base + D_ * D_ + D_ + 1) * 64);
        for (int jc = 0; jc < JP_ / 4; ++jc) {
            float4 v0 = P0[jc], v1 = P1[jc], v2 = P2[jc], v3 = P3[jc];
            float4 v4 = P4[jc], v5 = P5[jc], v6 = P6[jc], v7 = P7[jc];
            float a0 = w000 * v0.x + w001 * v1.x + w010 * v2.x + w011 * v3.x +
                       w100 * v4.x + w101 * v5.x + w110 * v6.x + w111 * v7.x;
            float a1 = w000 * v0.y + w001 * v1.y + w010 * v2.y + w011 * v3.y +
                       w100 * v4.y + w101 * v5.y + w110 * v6.y + w111 * v7.y;
            float a2 = w000 * v0.z + w001 * v1.z + w010 * v2.z + w011 * v3.z +
                       w100 * v4.z + w101 * v5.z + w110 * v6.z + w111 * v7.z;
            float a3 = w000 * v0.w + w001 * v1.w + w010 * v2.w + w011 * v3.w +
                       w100 * v4.w + w101 * v5.w + w110 * v6.w + w111 * v7.w;
            wsum += a0 + a1 + a2 + a3;
            const float* tr = tb + (jc * 4) * 16;
#pragma unroll
            for (int r = 0; r < 16; ++r) T[r] += a0 * tr[r];
#pragma unroll
            for (int r = 0; r < 16; ++r) T[r] += a1 * tr[16 + r];
#pragma unroll
            for (int r = 0; r < 16; ++r) T[r] += a2 * tr[32 + r];
#pragma unroll
            for (int r = 0; r < 16; ++r) T[r] += a3 * tr[48 + r];
        }
    }

    float inv = 1.f / fmaxf(wsum, 1e-8f);
#pragma unroll
    for (int r = 0; r < 16; ++r) T[r] *= inv;

    out_posed[3 * i + 0] = T[0] * x0 + T[1] * x1 + T[2] * x2 + T[3];
    out_posed[3 * i + 1] = T[4] * x0 + T[5] * x1 + T[6] * x2 + T[7];
    out_posed[3 * i + 2] = T[8] * x0 + T[9] * x1 + T[10] * x2 + T[11];

    float4* to = (float4*)(out_T + (size_t)i * 16);
    to[0] = make_float4(T[0], T[1], T[2], T[3]);
    to[1] = make_float4(T[4], T[5], T[6], T[7]);
    to[2] = make_float4(T[8], T[9], T[10], T[11]);
    to[3] = make_float4(T[12], T[13], T[14], T[15]);
}

extern "C" void kernel_launch(void* const* d_in, const int* in_sizes, int n_in,
                              void* d_out, int out_size, void* d_ws, size_t ws_size,
                              hipStream_t stream) {
    const float* pts      = (const float*)d_in[0];
    const float* betas    = (const float*)d_in[1];
    const float* pf       = (const float*)d_in[2];
    const float* spdir    = (const float*)d_in[3];
    const float* podir    = (const float*)d_in[4];
    const int*   faces    = (const int*)d_in[5];
    const float* tfs_A    = (const float*)d_in[6];
    const float* tfs_inv  = (const float*)d_in[7];
    const float* poseoff  = (const float*)d_in[8];
    const float* lbsw     = (const float*)d_in[9];
    const float* vox      = (const float*)d_in[10];
    const float* vscale   = (const float*)d_in[11];
    const float* voffset  = (const float*)d_in[12];
    const int*   mask     = (const int*)d_in[13];

    // workspace layout
    float* vox_t   = (float*)d_ws;                                   // 64MB
    float* off_full = (float*)((char*)d_ws + (size_t)D3_ * 64 * 4);  // 502,800B
    float* tfsP    = off_full + (size_t)B_ * COLS_;                  // 14,336B

    float* out_posed = (float*)d_out;
    float* out_T     = out_posed + (size_t)B_ * N_ * 3;

    k_vox_t<<<D3_ / 64, 256, 0, stream>>>(vox, vox_t);
    k_off_init<<<(COLS_ + 255) / 256, 256, 0, stream>>>(betas, spdir, off_full);
    dim3 gpose((COLS_ + 255) / 256, 8);
    k_off_pose<<<gpose, 256, 0, stream>>>(pf, podir, off_full);
    k_tfs<<<(B_ * JP_ * 16 + 255) / 256, 256, 0, stream>>>(tfs_A, tfs_inv, tfsP);
    k_main<<<(B_ * N_) / 256, 256, 0, stream>>>(
        pts, faces, poseoff, lbsw, mask, vscale, voffset, off_full, tfsP,
        vox_t, out_posed, out_T);
}

// Round 2
// 582.079 us; speedup vs baseline: 1.0401x; 1.0401x over previous
//
#include <hip/hip_runtime.h>
#include <hip/hip_bf16.h>

#define B_  4
#define N_  131072
#define M_  10475
#define J_  55
#define JP_ 56        // padded J (pad entries are zero)
#define D_  64
#define D3_ 262144    // 64^3
#define PF_ 486
#define COLS_ 31425   // M*3

#define BL16(u) __uint_as_float((u) << 16)
#define BH16(u) __uint_as_float((u) & 0xffff0000u)

__device__ __forceinline__ unsigned short f2bf(float v) {
    unsigned u = __float_as_uint(v);
    u += 0x7fffu + ((u >> 16) & 1u);   // round-to-nearest-even
    return (unsigned short)(u >> 16);
}

// ---------------- off_full init: shape part (betas . spdir) ----------------
__global__ void k_off_init(const float* __restrict__ betas,
                           const float* __restrict__ spdir,
                           float* __restrict__ off_full) {
    int col = blockIdx.x * 256 + threadIdx.x;
    if (col >= COLS_) return;
    float sp[10];
#pragma unroll
    for (int l = 0; l < 10; ++l) sp[l] = spdir[col * 10 + l];
#pragma unroll
    for (int b = 0; b < B_; ++b) {
        float s = 0.f;
#pragma unroll
        for (int l = 0; l < 10; ++l) s += betas[b * 10 + l] * sp[l];
        off_full[b * COLS_ + col] = s;
    }
}

// ---------------- off_full pose part: pf @ podir, p-chunked atomics --------
__global__ void k_off_pose(const float* __restrict__ pf,
                           const float* __restrict__ podir,
                           float* __restrict__ off_full) {
    int col = blockIdx.x * 256 + threadIdx.x;
    if (col >= COLS_) return;
    int pc = blockIdx.y;
    int p0 = pc * 61;
    int p1 = p0 + 61; if (p1 > PF_) p1 = PF_;
    float a0 = 0.f, a1 = 0.f, a2 = 0.f, a3 = 0.f;
    for (int p = p0; p < p1; ++p) {
        float v = podir[(size_t)p * COLS_ + col];
        a0 += pf[0 * PF_ + p] * v;
        a1 += pf[1 * PF_ + p] * v;
        a2 += pf[2 * PF_ + p] * v;
        a3 += pf[3 * PF_ + p] * v;
    }
    atomicAdd(&off_full[0 * COLS_ + col], a0);
    atomicAdd(&off_full[1 * COLS_ + col], a1);
    atomicAdd(&off_full[2 * COLS_ + col], a2);
    atomicAdd(&off_full[3 * COLS_ + col], a3);
}

// ---------------- tfs = A @ A_inv, padded to JP_ joints --------------------
__global__ void k_tfs(const float* __restrict__ A,
                      const float* __restrict__ Ainv,
                      float* __restrict__ tfsP) {
    int tid = blockIdx.x * 256 + threadIdx.x;
    if (tid >= B_ * JP_ * 16) return;
    int rc = tid & 15;
    int jb = tid >> 4;
    int j = jb % JP_;
    int b = jb / JP_;
    float v = 0.f;
    if (j < J_) {
        int r = rc >> 2, c = rc & 3;
#pragma unroll
        for (int k = 0; k < 4; ++k)
            v += A[((b * J_ + j) * 4 + r) * 4 + k] * Ainv[(j * 4 + k) * 4 + c];
    }
    tfsP[tid] = v;
}

// -------- voxel transpose+cast: [J][D3] fp32 -> [D3][64] bf16 (j-padded) ---
__global__ void k_vox_t(const float* __restrict__ vox,
                        unsigned short* __restrict__ vox_tb) {
    __shared__ float tile[64 * 65];
    int fid0 = blockIdx.x * 64;
    int t = threadIdx.x;
#pragma unroll
    for (int it = 0; it < 16; ++it) {
        int idx = it * 256 + t;
        int j = idx >> 6;
        int f = idx & 63;
        float v = (j < J_) ? vox[(size_t)j * D3_ + fid0 + f] : 0.f;
        tile[j * 65 + f] = v;
    }
    __syncthreads();
#pragma unroll
    for (int it = 0; it < 16; ++it) {
        int idx = it * 256 + t;
        int f = idx >> 6;
        int j = idx & 63;
        vox_tb[(size_t)(fid0 + f) * 64 + j] = f2bf(tile[j * 65 + f]);
    }
}

// ---------------- lbsw prepack: [N][55] fp32 -> [N][64] bf16 ---------------
__global__ void k_lbsw_pack(const float* __restrict__ lbsw,
                            unsigned short* __restrict__ lbswP) {
    int idx = blockIdx.x * 256 + threadIdx.x;   // over N*64
    int n = idx >> 6, j = idx & 63;
    float v = (j < J_) ? lbsw[(size_t)n * J_ + j] : 0.f;
    lbswP[idx] = f2bf(v);
}

// ---------------- partition points by (b, mask) ----------------------------
__global__ void k_part(const int* __restrict__ mask, int* __restrict__ cnts,
                       int* __restrict__ listV, int* __restrict__ listL) {
    int i = blockIdx.x * 256 + threadIdx.x;     // i = b*N + n
    int n = i & (N_ - 1);
    int b = i >> 17;                            // uniform per block (512 blk/b)
    bool m = mask[i] > 0;
    unsigned long long bal = __ballot(m);
    int lane = threadIdx.x & 63;
    unsigned long long lt = ((unsigned long long)1 << lane) - 1ull;
    int c1 = __popcll(bal);
    int base0 = 0, base1 = 0;
    if (lane == 0) {
        base1 = atomicAdd(&cnts[b * 2 + 1], c1);
        base0 = atomicAdd(&cnts[b * 2 + 0], 64 - c1);
    }
    base1 = __shfl(base1, 0);
    base0 = __shfl(base0, 0);
    int p1 = __popcll(bal & lt);
    int p0 = lane - p1;
    if (m) listL[b * N_ + base1 + p1] = n;
    else   listV[b * N_ + base0 + p0] = n;
}

// ---------------- common per-point x computation ---------------------------
__device__ __forceinline__ void compute_x(
    int i, int n, const float* __restrict__ pts,
    const int* __restrict__ faces, const float* __restrict__ poseoff,
    const float* __restrict__ ob, float& px, float& py, float& pz,
    float& x0, float& x1, float& x2) {
    px = pts[3 * i + 0]; py = pts[3 * i + 1]; pz = pts[3 * i + 2];
    int f0 = faces[3 * n + 0], f1 = faces[3 * n + 1], f2 = faces[3 * n + 2];
    const float c3 = 1.f / 3.f;
    float ox = (ob[f0 * 3 + 0] + ob[f1 * 3 + 0] + ob[f2 * 3 + 0]) * c3;
    float oy = (ob[f0 * 3 + 1] + ob[f1 * 3 + 1] + ob[f2 * 3 + 1]) * c3;
    float oz = (ob[f0 * 3 + 2] + ob[f1 * 3 + 2] + ob[f2 * 3 + 2]) * c3;
    x0 = px + ox - poseoff[3 * n + 0];
    x1 = py + oy - poseoff[3 * n + 1];
    x2 = pz + oz - poseoff[3 * n + 2];
}

__device__ __forceinline__ void finish_point(
    int i, const float* T, float wsum, float x0, float x1, float x2,
    float* __restrict__ out_posed, float* __restrict__ out_T) {
    float inv = 1.f / fmaxf(wsum, 1e-8f);
    float t[16];
#pragma unroll
    for (int r = 0; r < 16; ++r) t[r] = T[r] * inv;
    out_posed[3 * i + 0] = t[0] * x0 + t[1] * x1 + t[2] * x2 + t[3];
    out_posed[3 * i + 1] = t[4] * x0 + t[5] * x1 + t[6] * x2 + t[7];
    out_posed[3 * i + 2] = t[8] * x0 + t[9] * x1 + t[10] * x2 + t[11];
    float4* to = (float4*)(out_T + (size_t)i * 16);
    to[0] = make_float4(t[0], t[1], t[2], t[3]);
    to[1] = make_float4(t[4], t[5], t[6], t[7]);
    to[2] = make_float4(t[8], t[9], t[10], t[11]);
    to[3] = make_float4(t[12], t[13], t[14], t[15]);
}

// ---------------- mask=0 points: trilinear voxel path ----------------------
__global__ __launch_bounds__(256) void k_main_vox(
    const float* __restrict__ pts, const int* __restrict__ faces,
    const float* __restrict__ poseoff, const float* __restrict__ vox_scale,
    const float* __restrict__ vox_offset, const float* __restrict__ off_full,
    const float* __restrict__ tfsP, const unsigned short* __restrict__ vox_tb,
    const int* __restrict__ cnts, const int* __restrict__ listV,
    float* __restrict__ out_posed, float* __restrict__ out_T) {
    int b = blockIdx.y;
    int cnt = cnts[b * 2 + 0];
    int idx = blockIdx.x * 256 + threadIdx.x;
    if (idx >= cnt) return;
    int n = listV[b * N_ + idx];
    int i = (b << 17) | n;

    float px, py, pz, x0, x1, x2;
    compute_x(i, n, pts, faces, poseoff, off_full + b * COLS_,
              px, py, pz, x0, x1, x2);

    float sx = vox_scale[0], sy = vox_scale[1], sz = vox_scale[2];
    float o0 = vox_offset[0], o1 = vox_offset[1], o2 = vox_offset[2];
    float gx = fminf(fmaxf(px * sx + o0, -1.f), 1.f);
    float gy = fminf(fmaxf(py * sy + o1, -1.f), 1.f);
    float gz = fminf(fmaxf(pz * sz + o2, -1.f), 1.f);
    float tx = (gx + 1.f) * 0.5f * (D_ - 1);
    float ty = (gy + 1.f) * 0.5f * (D_ - 1);
    float tz = (gz + 1.f) * 0.5f * (D_ - 1);
    int ix = (int)floorf(tx); if (ix > D_ - 2) ix = D_ - 2; if (ix < 0) ix = 0;
    int iy = (int)floorf(ty); if (iy > D_ - 2) iy = D_ - 2; if (iy < 0) iy = 0;
    int iz = (int)floorf(tz); if (iz > D_ - 2) iz = D_ - 2; if (iz < 0) iz = 0;
    float fx = tx - ix, fy = ty - iy, fz = tz - iz;
    int base = (ix * D_ + iy) * D_ + iz;

    float a[JP_];
#pragma unroll
    for (int j = 0; j < JP_; ++j) a[j] = 0.f;

    // corner-outer: each corner's 56 bf16 = one aligned 128B line, consumed
    // by 7 back-to-back uint4 loads (MSHR-coalesced, thrash-immune)
#pragma unroll
    for (int c = 0; c < 8; ++c) {
        int fid = base + ((c & 4) ? D_ * D_ : 0) + ((c & 2) ? D_ : 0) + (c & 1);
        float wc = ((c & 4) ? fx : 1.f - fx) * ((c & 2) ? fy : 1.f - fy) *
                   ((c & 1) ? fz : 1.f - fz);
        const uint4* R = (const uint4*)(vox_tb + (size_t)fid * 64);
#pragma unroll
        for (int k = 0; k < 7; ++k) {
            uint4 q = R[k];
            a[k * 8 + 0] += wc * BL16(q.x); a[k * 8 + 1] += wc * BH16(q.x);
            a[k * 8 + 2] += wc * BL16(q.y); a[k * 8 + 3] += wc * BH16(q.y);
            a[k * 8 + 4] += wc * BL16(q.z); a[k * 8 + 5] += wc * BH16(q.z);
            a[k * 8 + 6] += wc * BL16(q.w); a[k * 8 + 7] += wc * BH16(q.w);
        }
    }

    float wsum = 0.f;
#pragma unroll
    for (int j = 0; j < JP_; ++j) wsum += a[j];   // a[55] == 0 (pad)

    const float* tb = tfsP + b * (JP_ * 16);      // uniform -> s_load
    float T[16];
#pragma unroll
    for (int r = 0; r < 16; ++r) T[r] = 0.f;
#pragma unroll
    for (int j = 0; j < JP_; ++j) {
        float w = a[j];
#pragma unroll
        for (int r = 0; r < 16; ++r) T[r] += w * tb[j * 16 + r];
    }
    finish_point(i, T, wsum, x0, x1, x2, out_posed, out_T);
}

// ---------------- mask=1 points: lbsw path ---------------------------------
__global__ __launch_bounds__(256) void k_main_lbsw(
    const float* __restrict__ pts, const int* __restrict__ faces,
    const float* __restrict__ poseoff, const float* __restrict__ off_full,
    const float* __restrict__ tfsP, const unsigned short* __restrict__ lbswP,
    const int* __restrict__ cnts, const int* __restrict__ listL,
    float* __restrict__ out_posed, float* __restrict__ out_T) {
    int b = blockIdx.y;
    int cnt = cnts[b * 2 + 1];
    int idx = blockIdx.x * 256 + threadIdx.x;
    if (idx >= cnt) return;
    int n = listL[b * N_ + idx];
    int i = (b << 17) | n;

    float px, py, pz, x0, x1, x2;
    compute_x(i, n, pts, faces, poseoff, off_full + b * COLS_,
              px, py, pz, x0, x1, x2);

    const uint4* R = (const uint4*)(lbswP + (size_t)n * 64);  // one 128B line
    const float* tb = tfsP + b * (JP_ * 16);                  // uniform -> s_load
    float T[16];
#pragma unroll
    for (int r = 0; r < 16; ++r) T[r] = 0.f;
    float wsum = 0.f;
#pragma unroll
    for (int k = 0; k < 7; ++k) {
        uint4 q = R[k];
        float w8[8] = { BL16(q.x), BH16(q.x), BL16(q.y), BH16(q.y),
                        BL16(q.z), BH16(q.z), BL16(q.w), BH16(q.w) };
#pragma unroll
        for (int s = 0; s < 8; ++s) {
            float w = w8[s];
            wsum += w;
            const float* tr = tb + (k * 8 + s) * 16;
#pragma unroll
            for (int r = 0; r < 16; ++r) T[r] += w * tr[r];
        }
    }
    finish_point(i, T, wsum, x0, x1, x2, out_posed, out_T);
}

extern "C" void kernel_launch(void* const* d_in, const int* in_sizes, int n_in,
                              void* d_out, int out_size, void* d_ws, size_t ws_size,
                              hipStream_t stream) {
    const float* pts      = (const float*)d_in[0];
    const float* betas    = (const float*)d_in[1];
    const float* pf       = (const float*)d_in[2];
    const float* spdir    = (const float*)d_in[3];
    const float* podir    = (const float*)d_in[4];
    const int*   faces    = (const int*)d_in[5];
    const float* tfs_A    = (const float*)d_in[6];
    const float* tfs_inv  = (const float*)d_in[7];
    const float* poseoff  = (const float*)d_in[8];
    const float* lbsw     = (const float*)d_in[9];
    const float* vox      = (const float*)d_in[10];
    const float* vscale   = (const float*)d_in[11];
    const float* voffset  = (const float*)d_in[12];
    const int*   mask     = (const int*)d_in[13];

    // workspace layout (all 256B-aligned)
    char* w = (char*)d_ws;
    unsigned short* vox_tb = (unsigned short*)w;                 // 33,554,432 B
    unsigned short* lbswP  = (unsigned short*)(w + 33554432);    // 16,777,216 B
    float* off_full        = (float*)(w + 50331648);             //    502,800 B
    float* tfsP            = (float*)(w + 50834688);             //     14,336 B
    int*   cnts            = (int*)(w + 50849024);               //         32 B
    int*   listV           = (int*)(w + 50849280);               //  2,097,152 B
    int*   listL           = (int*)(w + 52946432);               //  2,097,152 B

    float* out_posed = (float*)d_out;
    float* out_T     = out_posed + (size_t)B_ * N_ * 3;

    hipMemsetAsync(cnts, 0, 32, stream);
    k_vox_t<<<D3_ / 64, 256, 0, stream>>>(vox, vox_tb);
    k_lbsw_pack<<<(N_ * 64) / 256, 256, 0, stream>>>(lbsw, lbswP);
    k_off_init<<<(COLS_ + 255) / 256, 256, 0, stream>>>(betas, spdir, off_full);
    dim3 gpose((COLS_ + 255) / 256, 8);
    k_off_pose<<<gpose, 256, 0, stream>>>(pf, podir, off_full);
    k_tfs<<<(B_ * JP_ * 16 + 255) / 256, 256, 0, stream>>>(tfs_A, tfs_inv, tfsP);
    k_part<<<(B_ * N_) / 256, 256, 0, stream>>>(mask, cnts, listV, listL);
    dim3 gmain(N_ / 256, B_);
    k_main_vox<<<gmain, 256, 0, stream>>>(pts, faces, poseoff, vscale, voffset,
                                          off_full, tfsP, vox_tb, cnts, listV,
                                          out_posed, out_T);
    k_main_lbsw<<<gmain, 256, 0, stream>>>(pts, faces, poseoff, off_full, tfsP,
                                           lbswP, cnts, listL, out_posed, out_T);
}

// Round 3
// 403.472 us; speedup vs baseline: 1.5005x; 1.4427x over previous
//
#include <hip/hip_runtime.h>
#include <hip/hip_bf16.h>

#define B_  4
#define N_  131072
#define M_  10475
#define J_  55
#define JP_ 56        // padded J (pad entries are zero)
#define D_  64
#define D3_ 262144    // 64^3
#define PF_ 486
#define COLS_ 31425   // M*3

#define BL16(u) __uint_as_float((u) << 16)
#define BH16(u) __uint_as_float((u) & 0xffff0000u)

// counter c for batch b lives at cnts[(b*2+c)*32] -- one 128B line per counter
#define CNT(b, c) ((b * 2 + c) * 32)

__device__ __forceinline__ unsigned short f2bf(float v) {
    unsigned u = __float_as_uint(v);
    u += 0x7fffu + ((u >> 16) & 1u);   // round-to-nearest-even
    return (unsigned short)(u >> 16);
}

// ---------------- off_full init: shape part (betas . spdir) ----------------
__global__ void k_off_init(const float* __restrict__ betas,
                           const float* __restrict__ spdir,
                           float* __restrict__ off_full) {
    int col = blockIdx.x * 256 + threadIdx.x;
    if (col >= COLS_) return;
    float sp[10];
#pragma unroll
    for (int l = 0; l < 10; ++l) sp[l] = spdir[col * 10 + l];
#pragma unroll
    for (int b = 0; b < B_; ++b) {
        float s = 0.f;
#pragma unroll
        for (int l = 0; l < 10; ++l) s += betas[b * 10 + l] * sp[l];
        off_full[b * COLS_ + col] = s;
    }
}

// ---------------- off_full pose part: pf @ podir, p-chunked atomics --------
__global__ void k_off_pose(const float* __restrict__ pf,
                           const float* __restrict__ podir,
                           float* __restrict__ off_full) {
    int col = blockIdx.x * 256 + threadIdx.x;
    if (col >= COLS_) return;
    int pc = blockIdx.y;
    int p0 = pc * 61;
    int p1 = p0 + 61; if (p1 > PF_) p1 = PF_;
    float a0 = 0.f, a1 = 0.f, a2 = 0.f, a3 = 0.f;
    for (int p = p0; p < p1; ++p) {
        float v = podir[(size_t)p * COLS_ + col];
        a0 += pf[0 * PF_ + p] * v;
        a1 += pf[1 * PF_ + p] * v;
        a2 += pf[2 * PF_ + p] * v;
        a3 += pf[3 * PF_ + p] * v;
    }
    atomicAdd(&off_full[0 * COLS_ + col], a0);
    atomicAdd(&off_full[1 * COLS_ + col], a1);
    atomicAdd(&off_full[2 * COLS_ + col], a2);
    atomicAdd(&off_full[3 * COLS_ + col], a3);
}

// ---------------- tfs = A @ A_inv, padded to JP_ joints --------------------
__global__ void k_tfs(const float* __restrict__ A,
                      const float* __restrict__ Ainv,
                      float* __restrict__ tfsP) {
    int tid = blockIdx.x * 256 + threadIdx.x;
    if (tid >= B_ * JP_ * 16) return;
    int rc = tid & 15;
    int jb = tid >> 4;
    int j = jb % JP_;
    int b = jb / JP_;
    float v = 0.f;
    if (j < J_) {
        int r = rc >> 2, c = rc & 3;
#pragma unroll
        for (int k = 0; k < 4; ++k)
            v += A[((b * J_ + j) * 4 + r) * 4 + k] * Ainv[(j * 4 + k) * 4 + c];
    }
    tfsP[tid] = v;
}

// -------- voxel transpose+cast: [J][D3] fp32 -> [D3][64] bf16 (j-padded) ---
__global__ void k_vox_t(const float* __restrict__ vox,
                        unsigned short* __restrict__ vox_tb) {
    __shared__ float tile[64 * 65];
    int fid0 = blockIdx.x * 64;
    int t = threadIdx.x;
#pragma unroll
    for (int it = 0; it < 16; ++it) {
        int idx = it * 256 + t;
        int j = idx >> 6;
        int f = idx & 63;
        float v = (j < J_) ? vox[(size_t)j * D3_ + fid0 + f] : 0.f;
        tile[j * 65 + f] = v;
    }
    __syncthreads();
#pragma unroll
    for (int it = 0; it < 16; ++it) {
        int idx = it * 256 + t;
        int f = idx >> 6;
        int j = idx & 63;
        vox_tb[(size_t)(fid0 + f) * 64 + j] = f2bf(tile[j * 65 + f]);
    }
}

// ---------------- lbsw prepack: [N][55] fp32 -> [N][64] bf16 ---------------
__global__ void k_lbsw_pack(const float* __restrict__ lbsw,
                            unsigned short* __restrict__ lbswP) {
    int idx = blockIdx.x * 256 + threadIdx.x;   // over N*64
    int n = idx >> 6, j = idx & 63;
    float v = (j < J_) ? lbsw[(size_t)n * J_ + j] : 0.f;
    lbswP[idx] = f2bf(v);
}

// ---------------- partition points by (b, mask) ----------------------------
// block-aggregated atomics (2 per block, not 2 per wave) + 128B-padded
// counters: kills the same-line atomic serialization seen in R2 (189us)
__global__ void k_part(const int* __restrict__ mask, int* __restrict__ cnts,
                       int* __restrict__ listV, int* __restrict__ listL) {
    __shared__ int wc1[4];
    __shared__ int base0s, base1s;
    int i = blockIdx.x * 256 + threadIdx.x;     // i = b*N + n
    int n = i & (N_ - 1);
    int b = i >> 17;                            // uniform per block (512 blk/b)
    bool m = mask[i] > 0;
    unsigned long long bal = __ballot(m);
    int lane = threadIdx.x & 63;
    int wid = threadIdx.x >> 6;
    int c1 = __popcll(bal);
    if (lane == 0) wc1[wid] = c1;
    __syncthreads();
    if (threadIdx.x == 0) {
        int t1 = wc1[0] + wc1[1] + wc1[2] + wc1[3];
        base1s = atomicAdd(&cnts[CNT(b, 1)], t1);
        base0s = atomicAdd(&cnts[CNT(b, 0)], 256 - t1);
    }
    __syncthreads();
    int pre1 = 0;
#pragma unroll
    for (int k = 0; k < 4; ++k) pre1 += (k < wid) ? wc1[k] : 0;
    int pre0 = wid * 64 - pre1;
    unsigned long long lt = ((unsigned long long)1 << lane) - 1ull;
    int p1 = __popcll(bal & lt);
    int p0 = lane - p1;
    if (m) listL[b * N_ + base1s + pre1 + p1] = n;
    else   listV[b * N_ + base0s + pre0 + p0] = n;
}

// ---------------- common per-point x computation ---------------------------
__device__ __forceinline__ void compute_x(
    int i, int n, const float* __restrict__ pts,
    const int* __restrict__ faces, const float* __restrict__ poseoff,
    const float* __restrict__ ob, float& px, float& py, float& pz,
    float& x0, float& x1, float& x2) {
    px = pts[3 * i + 0]; py = pts[3 * i + 1]; pz = pts[3 * i + 2];
    int f0 = faces[3 * n + 0], f1 = faces[3 * n + 1], f2 = faces[3 * n + 2];
    const float c3 = 1.f / 3.f;
    float ox = (ob[f0 * 3 + 0] + ob[f1 * 3 + 0] + ob[f2 * 3 + 0]) * c3;
    float oy = (ob[f0 * 3 + 1] + ob[f1 * 3 + 1] + ob[f2 * 3 + 1]) * c3;
    float oz = (ob[f0 * 3 + 2] + ob[f1 * 3 + 2] + ob[f2 * 3 + 2]) * c3;
    x0 = px + ox - poseoff[3 * n + 0];
    x1 = py + oy - poseoff[3 * n + 1];
    x2 = pz + oz - poseoff[3 * n + 2];
}

__device__ __forceinline__ void finish_point(
    int i, const float* T, float wsum, float x0, float x1, float x2,
    float* __restrict__ out_posed, float* __restrict__ out_T) {
    float inv = 1.f / fmaxf(wsum, 1e-8f);
    float t[16];
#pragma unroll
    for (int r = 0; r < 16; ++r) t[r] = T[r] * inv;
    out_posed[3 * i + 0] = t[0] * x0 + t[1] * x1 + t[2] * x2 + t[3];
    out_posed[3 * i + 1] = t[4] * x0 + t[5] * x1 + t[6] * x2 + t[7];
    out_posed[3 * i + 2] = t[8] * x0 + t[9] * x1 + t[10] * x2 + t[11];
    float4* to = (float4*)(out_T + (size_t)i * 16);
    to[0] = make_float4(t[0], t[1], t[2], t[3]);
    to[1] = make_float4(t[4], t[5], t[6], t[7]);
    to[2] = make_float4(t[8], t[9], t[10], t[11]);
    to[3] = make_float4(t[12], t[13], t[14], t[15]);
}

// ---------------- mask=0 points: trilinear voxel path ----------------------
__global__ __launch_bounds__(256) void k_main_vox(
    const float* __restrict__ pts, const int* __restrict__ faces,
    const float* __restrict__ poseoff, const float* __restrict__ vox_scale,
    const float* __restrict__ vox_offset, const float* __restrict__ off_full,
    const float* __restrict__ tfsP, const unsigned short* __restrict__ vox_tb,
    const int* __restrict__ cnts, const int* __restrict__ listV,
    float* __restrict__ out_posed, float* __restrict__ out_T) {
    int b = blockIdx.y;
    int cnt = cnts[CNT(b, 0)];
    int idx = blockIdx.x * 256 + threadIdx.x;
    if (idx >= cnt) return;
    int n = listV[b * N_ + idx];
    int i = (b << 17) | n;

    float px, py, pz, x0, x1, x2;
    compute_x(i, n, pts, faces, poseoff, off_full + b * COLS_,
              px, py, pz, x0, x1, x2);

    float sx = vox_scale[0], sy = vox_scale[1], sz = vox_scale[2];
    float o0 = vox_offset[0], o1 = vox_offset[1], o2 = vox_offset[2];
    float gx = fminf(fmaxf(px * sx + o0, -1.f), 1.f);
    float gy = fminf(fmaxf(py * sy + o1, -1.f), 1.f);
    float gz = fminf(fmaxf(pz * sz + o2, -1.f), 1.f);
    float tx = (gx + 1.f) * 0.5f * (D_ - 1);
    float ty = (gy + 1.f) * 0.5f * (D_ - 1);
    float tz = (gz + 1.f) * 0.5f * (D_ - 1);
    int ix = (int)floorf(tx); if (ix > D_ - 2) ix = D_ - 2; if (ix < 0) ix = 0;
    int iy = (int)floorf(ty); if (iy > D_ - 2) iy = D_ - 2; if (iy < 0) iy = 0;
    int iz = (int)floorf(tz); if (iz > D_ - 2) iz = D_ - 2; if (iz < 0) iz = 0;
    float fx = tx - ix, fy = ty - iy, fz = tz - iz;
    int base = (ix * D_ + iy) * D_ + iz;

    float a[JP_];
#pragma unroll
    for (int j = 0; j < JP_; ++j) a[j] = 0.f;

    // corner-outer: each corner's 56 bf16 = one aligned 128B line, consumed
    // by 7 back-to-back uint4 loads (MSHR-coalesced, thrash-immune)
#pragma unroll
    for (int c = 0; c < 8; ++c) {
        int fid = base + ((c & 4) ? D_ * D_ : 0) + ((c & 2) ? D_ : 0) + (c & 1);
        float wc = ((c & 4) ? fx : 1.f - fx) * ((c & 2) ? fy : 1.f - fy) *
                   ((c & 1) ? fz : 1.f - fz);
        const uint4* R = (const uint4*)(vox_tb + (size_t)fid * 64);
#pragma unroll
        for (int k = 0; k < 7; ++k) {
            uint4 q = R[k];
            a[k * 8 + 0] += wc * BL16(q.x); a[k * 8 + 1] += wc * BH16(q.x);
            a[k * 8 + 2] += wc * BL16(q.y); a[k * 8 + 3] += wc * BH16(q.y);
            a[k * 8 + 4] += wc * BL16(q.z); a[k * 8 + 5] += wc * BH16(q.z);
            a[k * 8 + 6] += wc * BL16(q.w); a[k * 8 + 7] += wc * BH16(q.w);
        }
    }

    float wsum = 0.f;
#pragma unroll
    for (int j = 0; j < JP_; ++j) wsum += a[j];   // a[55] == 0 (pad)

    const float* tb = tfsP + b * (JP_ * 16);      // uniform -> s_load
    float T[16];
#pragma unroll
    for (int r = 0; r < 16; ++r) T[r] = 0.f;
#pragma unroll
    for (int j = 0; j < JP_; ++j) {
        float w = a[j];
#pragma unroll
        for (int r = 0; r < 16; ++r) T[r] += w * tb[j * 16 + r];
    }
    finish_point(i, T, wsum, x0, x1, x2, out_posed, out_T);
}

// ---------------- mask=1 points: lbsw path ---------------------------------
__global__ __launch_bounds__(256) void k_main_lbsw(
    const float* __restrict__ pts, const int* __restrict__ faces,
    const float* __restrict__ poseoff, const float* __restrict__ off_full,
    const float* __restrict__ tfsP, const unsigned short* __restrict__ lbswP,
    const int* __restrict__ cnts, const int* __restrict__ listL,
    float* __restrict__ out_posed, float* __restrict__ out_T) {
    int b = blockIdx.y;
    int cnt = cnts[CNT(b, 1)];
    int idx = blockIdx.x * 256 + threadIdx.x;
    if (idx >= cnt) return;
    int n = listL[b * N_ + idx];
    int i = (b << 17) | n;

    float px, py, pz, x0, x1, x2;
    compute_x(i, n, pts, faces, poseoff, off_full + b * COLS_,
              px, py, pz, x0, x1, x2);

    const uint4* R = (const uint4*)(lbswP + (size_t)n * 64);  // one 128B line
    const float* tb = tfsP + b * (JP_ * 16);                  // uniform -> s_load
    float T[16];
#pragma unroll
    for (int r = 0; r < 16; ++r) T[r] = 0.f;
    float wsum = 0.f;
#pragma unroll
    for (int k = 0; k < 7; ++k) {
        uint4 q = R[k];
        float w8[8] = { BL16(q.x), BH16(q.x), BL16(q.y), BH16(q.y),
                        BL16(q.z), BH16(q.z), BL16(q.w), BH16(q.w) };
#pragma unroll
        for (int s = 0; s < 8; ++s) {
            float w = w8[s];
            wsum += w;
            const float* tr = tb + (k * 8 + s) * 16;
#pragma unroll
            for (int r = 0; r < 16; ++r) T[r] += w * tr[r];
        }
    }
    finish_point(i, T, wsum, x0, x1, x2, out_posed, out_T);
}

extern "C" void kernel_launch(void* const* d_in, const int* in_sizes, int n_in,
                              void* d_out, int out_size, void* d_ws, size_t ws_size,
                              hipStream_t stream) {
    const float* pts      = (const float*)d_in[0];
    const float* betas    = (const float*)d_in[1];
    const float* pf       = (const float*)d_in[2];
    const float* spdir    = (const float*)d_in[3];
    const float* podir    = (const float*)d_in[4];
    const int*   faces    = (const int*)d_in[5];
    const float* tfs_A    = (const float*)d_in[6];
    const float* tfs_inv  = (const float*)d_in[7];
    const float* poseoff  = (const float*)d_in[8];
    const float* lbsw     = (const float*)d_in[9];
    const float* vox      = (const float*)d_in[10];
    const float* vscale   = (const float*)d_in[11];
    const float* voffset  = (const float*)d_in[12];
    const int*   mask     = (const int*)d_in[13];

    // workspace layout (all 256B-aligned)
    char* w = (char*)d_ws;
    unsigned short* vox_tb = (unsigned short*)w;                 // 33,554,432 B
    unsigned short* lbswP  = (unsigned short*)(w + 33554432);    // 16,777,216 B
    float* off_full        = (float*)(w + 50331648);             //    502,800 B
    float* tfsP            = (float*)(w + 50834688);             //     14,336 B
    int*   cnts            = (int*)(w + 50849024);               //      1,024 B
    int*   listV           = (int*)(w + 50850304);               //  2,097,152 B
    int*   listL           = (int*)(w + 52947456);               //  2,097,152 B

    float* out_posed = (float*)d_out;
    float* out_T     = out_posed + (size_t)B_ * N_ * 3;

    hipMemsetAsync(cnts, 0, 1024, stream);
    k_vox_t<<<D3_ / 64, 256, 0, stream>>>(vox, vox_tb);
    k_lbsw_pack<<<(N_ * 64) / 256, 256, 0, stream>>>(lbsw, lbswP);
    k_off_init<<<(COLS_ + 255) / 256, 256, 0, stream>>>(betas, spdir, off_full);
    dim3 gpose((COLS_ + 255) / 256, 8);
    k_off_pose<<<gpose, 256, 0, stream>>>(pf, podir, off_full);
    k_tfs<<<(B_ * JP_ * 16 + 255) / 256, 256, 0, stream>>>(tfs_A, tfs_inv, tfsP);
    k_part<<<(B_ * N_) / 256, 256, 0, stream>>>(mask, cnts, listV, listL);
    dim3 gmain(N_ / 256, B_);
    k_main_vox<<<gmain, 256, 0, stream>>>(pts, faces, poseoff, vscale, voffset,
                                          off_full, tfsP, vox_tb, cnts, listV,
                                          out_posed, out_T);
    k_main_lbsw<<<gmain, 256, 0, stream>>>(pts, faces, poseoff, off_full, tfsP,
                                           lbswP, cnts, listL, out_posed, out_T);
}